// Round 5
// baseline (146.782 us; speedup 1.0000x reference)
//
#include <hip/hip_runtime.h>

// Chamfer distance loss over equal-size clusters (C=128, P=1024, DIM=3).
// Reference excludes the highest cluster id -> clusters 0..126 contribute.
//
// R5 = R4 structure with the spill fixed. R4's failure: Q=16 register arrays
// spilled (VGPR capped at 64 -> 130 MB scratch writes). Fixes:
//  - __launch_bounds__(1024, 4): 4 waves/EU == 1 block/CU for a 16-wave
//    block -> VGPR cap 128.
//  - qn[] array dropped; |a|^2 recomputed at store time from the -2-scaled
//    coords (qn = 0.25*(qx^2+qy^2+qz^2)) -> ~16 fewer live VGPRs.
// Structure: one block per (cluster, direction) = 254 blocks x 1024 threads.
// Thread (qi = tid&63, seg = tid>>6) owns Q=16 queries {k*64+qi}, sweeps
// targets [seg*64, (seg+1)*64). SoA plane LDS (sx/sy/sz/sh), ds_read_b128
// = 4 targets/plane, wave-uniform (broadcast). Packed fp32 v_pk_fma_f32:
// 6 pk_fma + 2 v_min3 per 4 pairs per query = 2.0 VALU/pair.
// Cross-seg combine: LDS atomicMin on uint bit patterns (d >= 0).

#define PTS  1024
#define ACTIVE_CLUSTERS 127
#define QG   64            // queries per k-slice (= threads per segment)
#define Q    16            // queries per thread   (Q*QG == PTS)
#define SEG  16            // target segments      (SEG*QG == TPB)
#define TPB  1024
#define TSEG (PTS / SEG)   // 64 targets per segment

typedef float v2f __attribute__((ext_vector_type(2)));

static __device__ __forceinline__ v2f splat2(float a) {
    v2f r; r.x = a; r.y = a; return r;
}

__global__ __launch_bounds__(TPB, 4) void chamfer_kernel(
    const float* __restrict__ pts_in,
    const float* __restrict__ pts_out,
    float* __restrict__ out)
{
    const int c   = blockIdx.x >> 1;
    const int dir = blockIdx.x & 1;

    const float* __restrict__ query  = dir ? pts_out : pts_in;
    const float* __restrict__ target = dir ? pts_in  : pts_out;

    __shared__ __align__(16) float sx[PTS];
    __shared__ __align__(16) float sy[PTS];
    __shared__ __align__(16) float sz[PTS];
    __shared__ __align__(16) float sh[PTS];
    __shared__ unsigned colmin[PTS];
    __shared__ float wsum[16];

    const int tid = threadIdx.x;
    const int qi  = tid & (QG - 1);
    const int seg = tid >> 6;
    const size_t base = (size_t)c * PTS * 3;

    colmin[tid] = 0x7f7fffffu;  // FLT_MAX bits

    // Stage targets into plane (SoA) LDS layout.
    {
        const float* tp = target + base + (size_t)tid * 3;
        float x = tp[0], y = tp[1], z = tp[2];
        sx[tid] = x; sy[tid] = y; sz[tid] = z;
        sh[tid] = fmaf(x, x, fmaf(y, y, z * z));
    }

    // Load Q query points as -2*coords only (|a|^2 re-derived at the end).
    float qx[Q], qy[Q], qz[Q], mn[Q];
    #pragma unroll
    for (int k = 0; k < Q; ++k) {
        const float* qp = query + base + (size_t)(k * QG + qi) * 3;
        qx[k] = -2.0f * qp[0];
        qy[k] = -2.0f * qp[1];
        qz[k] = -2.0f * qp[2];
        mn[k] = 3.4e38f;
    }
    __syncthreads();

    // Sweep this segment's 64 targets, 4 at a time (b128 per plane).
    const int j0 = seg * TSEG;
    #pragma unroll 2
    for (int jj = 0; jj < TSEG; jj += 4) {
        const float4 bx = *(const float4*)&sx[j0 + jj];
        const float4 by = *(const float4*)&sy[j0 + jj];
        const float4 bz = *(const float4*)&sz[j0 + jj];
        const float4 bh = *(const float4*)&sh[j0 + jj];
        v2f bx01; bx01.x = bx.x; bx01.y = bx.y;
        v2f bx23; bx23.x = bx.z; bx23.y = bx.w;
        v2f by01; by01.x = by.x; by01.y = by.y;
        v2f by23; by23.x = by.z; by23.y = by.w;
        v2f bz01; bz01.x = bz.x; bz01.y = bz.y;
        v2f bz23; bz23.x = bz.z; bz23.y = bz.w;
        v2f bh01; bh01.x = bh.x; bh01.y = bh.y;
        v2f bh23; bh23.x = bh.z; bh23.y = bh.w;
        #pragma unroll
        for (int k = 0; k < Q; ++k) {
            v2f s01 = __builtin_elementwise_fma(splat2(qx[k]), bx01, bh01);
            s01 = __builtin_elementwise_fma(splat2(qy[k]), by01, s01);
            s01 = __builtin_elementwise_fma(splat2(qz[k]), bz01, s01);
            v2f s23 = __builtin_elementwise_fma(splat2(qx[k]), bx23, bh23);
            s23 = __builtin_elementwise_fma(splat2(qy[k]), by23, s23);
            s23 = __builtin_elementwise_fma(splat2(qz[k]), bz23, s23);
            mn[k] = fminf(fminf(s01.x, s01.y), mn[k]);   // v_min3_f32
            mn[k] = fminf(fminf(s23.x, s23.y), mn[k]);   // v_min3_f32
        }
    }

    // Cross-seg combine: LDS atomicMin on uint bit patterns (d >= 0).
    // |a|^2 = 0.25*(qx^2+qy^2+qz^2) since qx = -2*ax etc.
    #pragma unroll
    for (int k = 0; k < Q; ++k) {
        float n2 = fmaf(qx[k], qx[k], fmaf(qy[k], qy[k], qz[k] * qz[k]));
        float v  = fmaf(0.25f, n2, mn[k]);
        atomicMin(&colmin[k * QG + qi], __float_as_uint(v));
    }
    __syncthreads();

    // Sum the 1024 per-query mins: wave shuffle, cross-wave, one atomicAdd.
    float v = __uint_as_float(colmin[tid]);
    #pragma unroll
    for (int off = 32; off > 0; off >>= 1)
        v += __shfl_down(v, off, 64);

    const int wave = tid >> 6;
    const int lane = tid & 63;
    if (lane == 0) wsum[wave] = v;
    __syncthreads();

    if (wave == 0) {
        float t = (lane < 16) ? wsum[lane] : 0.0f;
        #pragma unroll
        for (int off = 8; off > 0; off >>= 1)
            t += __shfl_down(t, off, 64);
        if (lane == 0) atomicAdd(out, t);
    }
}

extern "C" void kernel_launch(void* const* d_in, const int* in_sizes, int n_in,
                              void* d_out, int out_size, void* d_ws, size_t ws_size,
                              hipStream_t stream) {
    const float* input_points  = (const float*)d_in[0];
    const float* output_points = (const float*)d_in[2];
    float* out = (float*)d_out;

    hipMemsetAsync(out, 0, sizeof(float), stream);

    chamfer_kernel<<<dim3(ACTIVE_CLUSTERS * 2), dim3(TPB), 0, stream>>>(
        input_points, output_points, out);
}

// Round 6
// 87.737 us; speedup vs baseline: 1.6730x; 1.6730x over previous
//
#include <hip/hip_runtime.h>

// Chamfer distance loss over equal-size clusters (C=128, P=1024, DIM=3).
// Reference excludes the highest cluster id -> clusters 0..126 contribute.
//
// R6 = R5 dataflow with the VGPR cap actually raised. R4/R5 failed because
// the allocator budgeted 8 waves/EU (64 VGPRs) for the 1024-thread block and
// spilled the Q=16 working set (~200 MB scratch traffic, VALUBusy 16%).
// __launch_bounds__(1024,4) did NOT raise the cap; here we pin it with the
// LLVM attribute amdgpu_waves_per_eu(4,4) -> exactly 4 waves/EU -> 128 VGPRs.
// Also removed the jj-loop unroll-by-2 (halves live packed-target regs).
//
// Structure: one block per (cluster, direction) = 254 blocks x 1024 threads.
// Thread (qi = tid&63, seg = tid>>6) owns Q=16 queries {k*64+qi}, sweeps
// targets [seg*64, (seg+1)*64). SoA plane LDS (sx/sy/sz/sh), ds_read_b128 =
// 4 targets/plane, wave-uniform broadcast -> 1024 b128/block, conflict-free.
// Packed fp32 v_pk_fma_f32: 6 pk_fma + 2 v_min3 per 4 pairs/query = 2.0
// VALU/pair. Cross-seg combine: LDS atomicMin on uint bit patterns (d >= 0).

#define PTS  1024
#define ACTIVE_CLUSTERS 127
#define QG   64            // queries per k-slice (= threads per segment)
#define Q    16            // queries per thread   (Q*QG == PTS)
#define SEG  16            // target segments      (SEG*QG == TPB)
#define TPB  1024
#define TSEG (PTS / SEG)   // 64 targets per segment

typedef float v2f __attribute__((ext_vector_type(2)));

static __device__ __forceinline__ v2f splat2(float a) {
    v2f r; r.x = a; r.y = a; return r;
}

__global__
__attribute__((amdgpu_flat_work_group_size(TPB, TPB), amdgpu_waves_per_eu(4, 4)))
void chamfer_kernel(
    const float* __restrict__ pts_in,
    const float* __restrict__ pts_out,
    float* __restrict__ out)
{
    const int c   = blockIdx.x >> 1;
    const int dir = blockIdx.x & 1;

    const float* __restrict__ query  = dir ? pts_out : pts_in;
    const float* __restrict__ target = dir ? pts_in  : pts_out;

    __shared__ __align__(16) float sx[PTS];
    __shared__ __align__(16) float sy[PTS];
    __shared__ __align__(16) float sz[PTS];
    __shared__ __align__(16) float sh[PTS];
    __shared__ unsigned colmin[PTS];
    __shared__ float wsum[16];

    const int tid = threadIdx.x;
    const int qi  = tid & (QG - 1);
    const int seg = tid >> 6;
    const size_t base = (size_t)c * PTS * 3;

    colmin[tid] = 0x7f7fffffu;  // FLT_MAX bits

    // Stage targets into plane (SoA) LDS layout.
    {
        const float* tp = target + base + (size_t)tid * 3;
        float x = tp[0], y = tp[1], z = tp[2];
        sx[tid] = x; sy[tid] = y; sz[tid] = z;
        sh[tid] = fmaf(x, x, fmaf(y, y, z * z));
    }

    // Load Q query points as -2*coords only (|a|^2 re-derived at the end).
    float qx[Q], qy[Q], qz[Q], mn[Q];
    #pragma unroll
    for (int k = 0; k < Q; ++k) {
        const float* qp = query + base + (size_t)(k * QG + qi) * 3;
        qx[k] = -2.0f * qp[0];
        qy[k] = -2.0f * qp[1];
        qz[k] = -2.0f * qp[2];
        mn[k] = 3.4e38f;
    }
    __syncthreads();

    // Sweep this segment's 64 targets, 4 at a time (one b128 per plane).
    const int j0 = seg * TSEG;
    #pragma unroll 1
    for (int jj = 0; jj < TSEG; jj += 4) {
        const float4 bx = *(const float4*)&sx[j0 + jj];
        const float4 by = *(const float4*)&sy[j0 + jj];
        const float4 bz = *(const float4*)&sz[j0 + jj];
        const float4 bh = *(const float4*)&sh[j0 + jj];
        v2f bx01; bx01.x = bx.x; bx01.y = bx.y;
        v2f bx23; bx23.x = bx.z; bx23.y = bx.w;
        v2f by01; by01.x = by.x; by01.y = by.y;
        v2f by23; by23.x = by.z; by23.y = by.w;
        v2f bz01; bz01.x = bz.x; bz01.y = bz.y;
        v2f bz23; bz23.x = bz.z; bz23.y = bz.w;
        v2f bh01; bh01.x = bh.x; bh01.y = bh.y;
        v2f bh23; bh23.x = bh.z; bh23.y = bh.w;
        #pragma unroll
        for (int k = 0; k < Q; ++k) {
            v2f s01 = __builtin_elementwise_fma(splat2(qx[k]), bx01, bh01);
            s01 = __builtin_elementwise_fma(splat2(qy[k]), by01, s01);
            s01 = __builtin_elementwise_fma(splat2(qz[k]), bz01, s01);
            v2f s23 = __builtin_elementwise_fma(splat2(qx[k]), bx23, bh23);
            s23 = __builtin_elementwise_fma(splat2(qy[k]), by23, s23);
            s23 = __builtin_elementwise_fma(splat2(qz[k]), bz23, s23);
            mn[k] = fminf(fminf(s01.x, s01.y), mn[k]);   // v_min3_f32
            mn[k] = fminf(fminf(s23.x, s23.y), mn[k]);   // v_min3_f32
        }
    }

    // Cross-seg combine: LDS atomicMin on uint bit patterns (d >= 0).
    // |a|^2 = 0.25*(qx^2+qy^2+qz^2) since qx = -2*ax etc.
    #pragma unroll
    for (int k = 0; k < Q; ++k) {
        float n2 = fmaf(qx[k], qx[k], fmaf(qy[k], qy[k], qz[k] * qz[k]));
        float v  = fmaf(0.25f, n2, mn[k]);
        atomicMin(&colmin[k * QG + qi], __float_as_uint(v));
    }
    __syncthreads();

    // Sum the 1024 per-query mins: wave shuffle, cross-wave, one atomicAdd.
    float v = __uint_as_float(colmin[tid]);
    #pragma unroll
    for (int off = 32; off > 0; off >>= 1)
        v += __shfl_down(v, off, 64);

    const int wave = tid >> 6;
    const int lane = tid & 63;
    if (lane == 0) wsum[wave] = v;
    __syncthreads();

    if (wave == 0) {
        float t = (lane < 16) ? wsum[lane] : 0.0f;
        #pragma unroll
        for (int off = 8; off > 0; off >>= 1)
            t += __shfl_down(t, off, 64);
        if (lane == 0) atomicAdd(out, t);
    }
}

extern "C" void kernel_launch(void* const* d_in, const int* in_sizes, int n_in,
                              void* d_out, int out_size, void* d_ws, size_t ws_size,
                              hipStream_t stream) {
    const float* input_points  = (const float*)d_in[0];
    const float* output_points = (const float*)d_in[2];
    float* out = (float*)d_out;

    hipMemsetAsync(out, 0, sizeof(float), stream);

    chamfer_kernel<<<dim3(ACTIVE_CLUSTERS * 2), dim3(TPB), 0, stream>>>(
        input_points, output_points, out);
}

// Round 7
// 87.165 us; speedup vs baseline: 1.6839x; 1.0066x over previous
//
#include <hip/hip_runtime.h>

// Chamfer distance loss over equal-size clusters (C=128, P=1024, DIM=3).
// Reference excludes the highest cluster id -> clusters 0..126 contribute.
//
// R7: retreat to a spill-immune, occupancy-first configuration.
//  - Grid: 508 blocks = (cluster, dir, query-half); 1024 threads each.
//    8128 waves -> ~8 waves/SIMD (R6 had 4 and a serial ds_read->VALU chain).
//  - Thread (qi = tid&63, seg = tid>>6) owns Q=8 queries of this block's
//    512-query half and sweeps targets [seg*64, (seg+1)*64).
//  - Register demand ~56 < the default 64-VGPR cap (8 waves/EU target):
//    no __launch_bounds__/waves_per_eu games, spill impossible by design.
//  - Scalar fma + v_min3 only (3.5 VALU/pair, predictable codegen; the R6
//    v2f packed path is suspected of mov-heavy scalarization).
//  - SoA plane LDS (sx/sy/sz/sh), ds_read_b128 = 4 targets/plane,
//    wave-uniform broadcast, conflict-free. 2048 b128/CU ~= 10 us < VALU.
//  - Cross-seg combine: LDS atomicMin on uint bit patterns (d >= 0);
//    |a|^2 re-derived from -2-scaled coords (saves 8 VGPRs).
// Floors: VALU ~12.9 us, LDS ~10.2 us -> expect 13-16 us at 8 waves/SIMD.

#define PTS   1024
#define ACTIVE_CLUSTERS 127
#define QHALF 512          // queries per block (half a cluster)
#define QG    64           // query-group width (threads per segment)
#define Q     8            // queries per thread (Q*QG == QHALF)
#define SEG   16           // target segments   (SEG*QG == TPB)
#define TPB   1024
#define TSEG  (PTS / SEG)  // 64 targets per segment

__global__ __launch_bounds__(TPB) void chamfer_kernel(
    const float* __restrict__ pts_in,
    const float* __restrict__ pts_out,
    float* __restrict__ out)
{
    const int b    = blockIdx.x;
    const int c    = b >> 2;          // 0..126
    const int dir  = (b >> 1) & 1;
    const int half = b & 1;

    const float* __restrict__ query  = dir ? pts_out : pts_in;
    const float* __restrict__ target = dir ? pts_in  : pts_out;

    __shared__ __align__(16) float sx[PTS];
    __shared__ __align__(16) float sy[PTS];
    __shared__ __align__(16) float sz[PTS];
    __shared__ __align__(16) float sh[PTS];
    __shared__ unsigned colmin[QHALF];
    __shared__ float wsum[16];

    const int tid = threadIdx.x;
    const int qi  = tid & (QG - 1);
    const int seg = tid >> 6;
    const size_t base = (size_t)c * PTS * 3;

    if (tid < QHALF) colmin[tid] = 0x7f7fffffu;  // FLT_MAX bits

    // Stage all 1024 targets into plane (SoA) LDS: one point per thread.
    {
        const float* tp = target + base + (size_t)tid * 3;
        float x = tp[0], y = tp[1], z = tp[2];
        sx[tid] = x; sy[tid] = y; sz[tid] = z;
        sh[tid] = fmaf(x, x, fmaf(y, y, z * z));
    }

    // Load Q query points as -2*coords (|a|^2 re-derived at the end).
    float qx[Q], qy[Q], qz[Q], mn[Q];
    #pragma unroll
    for (int k = 0; k < Q; ++k) {
        const float* qp = query + base
                        + (size_t)(half * QHALF + k * QG + qi) * 3;
        qx[k] = -2.0f * qp[0];
        qy[k] = -2.0f * qp[1];
        qz[k] = -2.0f * qp[2];
        mn[k] = 3.4e38f;
    }
    __syncthreads();

    // Sweep this segment's 64 targets, 4 at a time (one b128 per plane).
    const int j0 = seg * TSEG;
    #pragma unroll 1
    for (int jj = 0; jj < TSEG; jj += 4) {
        const float4 bx = *(const float4*)&sx[j0 + jj];
        const float4 by = *(const float4*)&sy[j0 + jj];
        const float4 bz = *(const float4*)&sz[j0 + jj];
        const float4 bh = *(const float4*)&sh[j0 + jj];
        #pragma unroll
        for (int k = 0; k < Q; ++k) {
            float s0 = fmaf(qx[k], bx.x, fmaf(qy[k], by.x, fmaf(qz[k], bz.x, bh.x)));
            float s1 = fmaf(qx[k], bx.y, fmaf(qy[k], by.y, fmaf(qz[k], bz.y, bh.y)));
            float s2 = fmaf(qx[k], bx.z, fmaf(qy[k], by.z, fmaf(qz[k], bz.z, bh.z)));
            float s3 = fmaf(qx[k], bx.w, fmaf(qy[k], by.w, fmaf(qz[k], bz.w, bh.w)));
            mn[k] = fminf(fminf(s0, s1), mn[k]);   // v_min3_f32
            mn[k] = fminf(fminf(s2, s3), mn[k]);   // v_min3_f32
        }
    }

    // Cross-seg combine: LDS atomicMin on uint bit patterns (d >= 0).
    // |a|^2 = 0.25*(qx^2+qy^2+qz^2) since qx = -2*ax etc.
    #pragma unroll
    for (int k = 0; k < Q; ++k) {
        float n2 = fmaf(qx[k], qx[k], fmaf(qy[k], qy[k], qz[k] * qz[k]));
        float v  = fmaf(0.25f, n2, mn[k]);
        atomicMin(&colmin[k * QG + qi], __float_as_uint(v));
    }
    __syncthreads();

    // Sum this block's 512 per-query mins; one atomicAdd per block.
    float v = (tid < QHALF) ? __uint_as_float(colmin[tid]) : 0.0f;
    #pragma unroll
    for (int off = 32; off > 0; off >>= 1)
        v += __shfl_down(v, off, 64);

    const int wave = tid >> 6;
    const int lane = tid & 63;
    if (lane == 0) wsum[wave] = v;
    __syncthreads();

    if (wave == 0) {
        float t = (lane < 16) ? wsum[lane] : 0.0f;
        #pragma unroll
        for (int off = 8; off > 0; off >>= 1)
            t += __shfl_down(t, off, 64);
        if (lane == 0) atomicAdd(out, t);
    }
}

extern "C" void kernel_launch(void* const* d_in, const int* in_sizes, int n_in,
                              void* d_out, int out_size, void* d_ws, size_t ws_size,
                              hipStream_t stream) {
    const float* input_points  = (const float*)d_in[0];
    const float* output_points = (const float*)d_in[2];
    float* out = (float*)d_out;

    hipMemsetAsync(out, 0, sizeof(float), stream);

    chamfer_kernel<<<dim3(ACTIVE_CLUSTERS * 2 * 2), dim3(TPB), 0, stream>>>(
        input_points, output_points, out);
}

// Round 8
// 86.203 us; speedup vs baseline: 1.7028x; 1.0112x over previous
//
#include <hip/hip_runtime.h>

// Chamfer distance loss over equal-size clusters (C=128, P=1024, DIM=3).
// Reference excludes the highest cluster id -> clusters 0..126 contribute.
//
// R8 = R7 with live register state cut decisively below the 64-VGPR cap.
// R3..R7 all plateaued ~30-33 us, ~2.5x the 12 us VALU floor; audit says
// R7's live set (32 query regs + 16 target regs + temps) sat AT the 64 cap
// -> inner-loop spill/remat. Fix: pair-packed AoSoA target layout in LDS:
//   st4[2p]   = (x_{2p}, x_{2p+1}, y_{2p}, y_{2p+1})
//   st4[2p+1] = (z_{2p}, z_{2p+1}, h_{2p}, h_{2p+1}),  h = |b|^2
// so an inner iteration needs 2 ds_read_b128 (8 regs) per 2 targets, still
// 1 b128 per target per wave, amortized over Q=8 queries/thread.
// Budget: 32 query + 16 target (unroll 2) + ~10 temps ~= 58 < 64.
//
// Grid: 508 blocks = (cluster, dir, query-half) x 1024 threads (16 waves,
// ~8 waves/SIMD, 2 blocks/CU). Thread (qi = tid&63, seg = tid>>6) owns Q=8
// queries of the block's 512-query half; its wave sweeps targets
// [seg*64, (seg+1)*64) = 32 pair-chunks. Wave-uniform LDS reads (broadcast,
// conflict-free). 7 VALU per 2 targets per query (6 fma + v_min3).
// Cross-seg combine: LDS atomicMin on uint bit patterns (d >= 0).

#define PTS   1024
#define ACTIVE_CLUSTERS 127
#define QHALF 512
#define QG    64
#define Q     8
#define SEG   16
#define TPB   1024
#define TSEG  (PTS / SEG)   // 64 targets per segment = 32 pair-chunks

__global__ __launch_bounds__(TPB) void chamfer_kernel(
    const float* __restrict__ pts_in,
    const float* __restrict__ pts_out,
    float* __restrict__ out)
{
    const int b    = blockIdx.x;
    const int c    = b >> 2;          // 0..126
    const int dir  = (b >> 1) & 1;
    const int half = b & 1;

    const float* __restrict__ query  = dir ? pts_out : pts_in;
    const float* __restrict__ target = dir ? pts_in  : pts_out;

    __shared__ __align__(16) float4 st4[PTS];   // 16 KB pair-packed targets
    __shared__ unsigned colmin[QHALF];
    __shared__ float wsum[16];

    const int tid = threadIdx.x;
    const int qi  = tid & (QG - 1);
    const int seg = tid >> 6;
    const size_t base = (size_t)c * PTS * 3;

    if (tid < QHALF) colmin[tid] = 0x7f7fffffu;  // FLT_MAX bits

    // Stage: thread p < 512 packs target pair (2p, 2p+1).
    if (tid < PTS / 2) {
        const float* tp = target + base + (size_t)tid * 6;
        float x0 = tp[0], y0 = tp[1], z0 = tp[2];
        float x1 = tp[3], y1 = tp[4], z1 = tp[5];
        float h0 = fmaf(x0, x0, fmaf(y0, y0, z0 * z0));
        float h1 = fmaf(x1, x1, fmaf(y1, y1, z1 * z1));
        st4[tid * 2]     = make_float4(x0, x1, y0, y1);
        st4[tid * 2 + 1] = make_float4(z0, z1, h0, h1);
    }

    // Load Q query points as -2*coords (|a|^2 re-derived at the end).
    float qx[Q], qy[Q], qz[Q], mn[Q];
    #pragma unroll
    for (int k = 0; k < Q; ++k) {
        const float* qp = query + base
                        + (size_t)(half * QHALF + k * QG + qi) * 3;
        qx[k] = -2.0f * qp[0];
        qy[k] = -2.0f * qp[1];
        qz[k] = -2.0f * qp[2];
        mn[k] = 3.4e38f;
    }
    __syncthreads();

    // Sweep this segment's 32 pair-chunks (64 targets), wave-uniform reads.
    const int p0 = seg * (TSEG / 2);
    #pragma unroll 2
    for (int p = 0; p < TSEG / 2; ++p) {
        const float4 c0 = st4[(p0 + p) * 2];      // x0 x1 y0 y1
        const float4 c1 = st4[(p0 + p) * 2 + 1];  // z0 z1 h0 h1
        #pragma unroll
        for (int k = 0; k < Q; ++k) {
            float s0 = fmaf(qx[k], c0.x, fmaf(qy[k], c0.z, fmaf(qz[k], c1.x, c1.z)));
            float s1 = fmaf(qx[k], c0.y, fmaf(qy[k], c0.w, fmaf(qz[k], c1.y, c1.w)));
            mn[k] = fminf(fminf(s0, s1), mn[k]);   // v_min3_f32
        }
    }

    // Cross-seg combine: LDS atomicMin on uint bit patterns (d >= 0).
    // |a|^2 = 0.25*(qx^2+qy^2+qz^2) since qx = -2*ax etc.
    #pragma unroll
    for (int k = 0; k < Q; ++k) {
        float n2 = fmaf(qx[k], qx[k], fmaf(qy[k], qy[k], qz[k] * qz[k]));
        float v  = fmaf(0.25f, n2, mn[k]);
        atomicMin(&colmin[k * QG + qi], __float_as_uint(v));
    }
    __syncthreads();

    // Sum this block's 512 per-query mins; one atomicAdd per block.
    float v = (tid < QHALF) ? __uint_as_float(colmin[tid]) : 0.0f;
    #pragma unroll
    for (int off = 32; off > 0; off >>= 1)
        v += __shfl_down(v, off, 64);

    const int wave = tid >> 6;
    const int lane = tid & 63;
    if (lane == 0) wsum[wave] = v;
    __syncthreads();

    if (wave == 0) {
        float t = (lane < 16) ? wsum[lane] : 0.0f;
        #pragma unroll
        for (int off = 8; off > 0; off >>= 1)
            t += __shfl_down(t, off, 64);
        if (lane == 0) atomicAdd(out, t);
    }
}

extern "C" void kernel_launch(void* const* d_in, const int* in_sizes, int n_in,
                              void* d_out, int out_size, void* d_ws, size_t ws_size,
                              hipStream_t stream) {
    const float* input_points  = (const float*)d_in[0];
    const float* output_points = (const float*)d_in[2];
    float* out = (float*)d_out;

    hipMemsetAsync(out, 0, sizeof(float), stream);

    chamfer_kernel<<<dim3(ACTIVE_CLUSTERS * 2 * 2), dim3(TPB), 0, stream>>>(
        input_points, output_points, out);
}